// Round 3
// baseline (1233.995 us; speedup 1.0000x reference)
//
#include <hip/hip_runtime.h>

#define HID 64

__device__ __forceinline__ float bf2f(unsigned short u) {
    return __uint_as_float(((unsigned)u) << 16);
}
__device__ __forceinline__ unsigned short f2bf(float f) {
    unsigned u = __float_as_uint(f);
    u += 0x7FFF + ((u >> 16) & 1);  // RNE
    return (unsigned short)(u >> 16);
}

// ================= CSR build =================
__global__ void zero2(int* counts, int* cursor, int n) {
    int i = blockIdx.x * blockDim.x + threadIdx.x;
    if (i < n) { counts[i] = 0; cursor[i] = 0; }
}

__global__ void hist_dst(const int* __restrict__ dst, int* counts, int E) {
    int e = blockIdx.x * blockDim.x + threadIdx.x;
    if (e < E) atomicAdd(&counts[dst[e]], 1);
}

// per-block inclusive scan of counts -> tmp; block totals -> bsum; also dinv
__global__ void scan1(const int* __restrict__ counts, int* __restrict__ tmp,
                      int* __restrict__ bsum, float* __restrict__ dinv, int n) {
    __shared__ int s[256];
    int t = threadIdx.x;
    int i = blockIdx.x * 256 + t;
    int v = (i < n) ? counts[i] : 0;
    if (i < n) dinv[i] = rsqrtf((float)v + 1.0f);  // deg incl. self-loop
    s[t] = v;
    __syncthreads();
#pragma unroll
    for (int d = 1; d < 256; d <<= 1) {
        int x = (t >= d) ? s[t - d] : 0;
        __syncthreads();
        s[t] += x;
        __syncthreads();
    }
    if (i < n) tmp[i] = s[t];
    if (t == 255) bsum[blockIdx.x] = s[255];
}

// exclusive scan of block sums (NB <= 256)
__global__ void scan2(const int* __restrict__ bsum, int* __restrict__ boff, int nb) {
    __shared__ int s[256];
    int t = threadIdx.x;
    s[t] = (t < nb) ? bsum[t] : 0;
    __syncthreads();
#pragma unroll
    for (int d = 1; d < 256; d <<= 1) {
        int x = (t >= d) ? s[t - d] : 0;
        __syncthreads();
        s[t] += x;
        __syncthreads();
    }
    if (t < nb) boff[t] = s[t] - bsum[t];  // exclusive
}

__global__ void scan3b(const int* __restrict__ counts, const int* __restrict__ tmp,
                       const int* __restrict__ boff, int* __restrict__ rowptr, int n, int E) {
    int b = blockIdx.x;
    int i = b * 256 + threadIdx.x;
    if (i < n) rowptr[i] = tmp[i] - counts[i] + boff[b];
    if (i == n - 1) rowptr[n] = tmp[i] + boff[b];  // == E
}

// bucket-fill CSR: col = src only (coef folded into hws)
__global__ void csr_fill(const int* __restrict__ eidx, const int* __restrict__ rowptr,
                         int* __restrict__ cursor, int* __restrict__ col, int E) {
    int e = blockIdx.x * blockDim.x + threadIdx.x;
    if (e >= E) return;
    int s = eidx[e];
    int d = eidx[E + e];
    int pos = rowptr[d] + atomicAdd(&cursor[d], 1);
    col[pos] = s;
}

// ================= dense ops =================
__global__ void input_proj(const float* __restrict__ x, const float* __restrict__ Win,
                           const float* __restrict__ bin, float* __restrict__ h, int n) {
    int t = blockIdx.x * blockDim.x + threadIdx.x;
    int v = t >> 6, j = t & 63;
    if (v >= n) return;
    float acc = bin[j];
#pragma unroll
    for (int k = 0; k < 4; ++k) acc += x[v * 4 + k] * Win[k * 64 + j];
    h[t] = acc;
}

// hws = (h @ W) * dinv, stored bf16. 32 rows/block, 8 rows/wave.
// W transposed in LDS stride 66 -> float2 reads, <=4-way alias (cheap).
__global__ void gemm_hws(const float* __restrict__ h, const float* __restrict__ W,
                         const float* __restrict__ dinv, unsigned short* __restrict__ hws,
                         int n) {
    __shared__ float wlT[64 * 66];
    __shared__ float hl[32 * 64];
    int tid = threadIdx.x;
#pragma unroll
    for (int i = 0; i < 16; ++i) {
        int idx = tid + 256 * i;   // idx = k*64 + j
        wlT[(idx & 63) * 66 + (idx >> 6)] = W[idx];
    }
    int v0 = blockIdx.x * 32;
#pragma unroll
    for (int i = 0; i < 8; ++i) {
        int idx = tid + 256 * i;   // 0..2047 ; row = idx>>6, col = idx&63
        int vv = v0 + (idx >> 6);
        hl[idx] = (vv < n) ? h[(size_t)vv * 64 + (idx & 63)] : 0.f;
    }
    __syncthreads();
    int j = tid & 63;
    int rb = (tid >> 6) * 8;       // this wave's local row base
    float acc[8] = {0.f, 0.f, 0.f, 0.f, 0.f, 0.f, 0.f, 0.f};
    const float2* wv2 = (const float2*)&wlT[j * 66];
#pragma unroll
    for (int k2 = 0; k2 < 32; ++k2) {
        float2 wv = wv2[k2];
#pragma unroll
        for (int r = 0; r < 8; ++r) {
            float2 hv = *(const float2*)&hl[(rb + r) * 64 + k2 * 2];  // broadcast
            acc[r] += hv.x * wv.x + hv.y * wv.y;
        }
    }
#pragma unroll
    for (int r = 0; r < 8; ++r) {
        int v = v0 + rb + r;
        if (v < n) hws[(size_t)v * 64 + j] = f2bf(acc[r] * dinv[v]);
    }
}

// pull aggregate (bf16 messages) + bias + BN(eval) + ReLU + residual; one wave per node
__global__ void gather_finalize(const int* __restrict__ rowptr, const int* __restrict__ col,
                                const unsigned short* __restrict__ hws,
                                const float* __restrict__ dinv, float* __restrict__ h,
                                const float* __restrict__ cb, const float* __restrict__ gamma,
                                const float* __restrict__ beta, const float* __restrict__ mean,
                                const float* __restrict__ var, int n) {
    int t = blockIdx.x * blockDim.x + threadIdx.x;
    int v = t >> 6;
    if (v >= n) return;
    int j = t & 63;
    int beg = rowptr[v], end = rowptr[v + 1];
    float sum = bf2f(hws[(size_t)v * 64 + j]);  // self-loop (already * dinv[v])
    int e = beg;
    for (; e + 3 < end; e += 4) {  // 4-way ILP
        int s0 = col[e], s1 = col[e + 1], s2 = col[e + 2], s3 = col[e + 3];
        float v0 = bf2f(hws[(size_t)s0 * 64 + j]);
        float v1 = bf2f(hws[(size_t)s1 * 64 + j]);
        float v2 = bf2f(hws[(size_t)s2 * 64 + j]);
        float v3 = bf2f(hws[(size_t)s3 * 64 + j]);
        sum += v0 + v1 + v2 + v3;
    }
    for (; e < end; ++e) sum += bf2f(hws[(size_t)col[e] * 64 + j]);
    float a = sum * dinv[v] + cb[j];
    a = (a - mean[j]) * rsqrtf(var[j] + 1e-5f) * gamma[j] + beta[j];
    a = fmaxf(a, 0.f);
    h[t] = a + h[t];  // residual: h still holds pre-conv value
}

// out = x + relu(h@W1+b1) @ W2 + b2 ; one wave per node
__global__ void mlp_out(const float* __restrict__ h, const float* __restrict__ x,
                        const float* __restrict__ W1, const float* __restrict__ b1,
                        const float* __restrict__ W2, const float* __restrict__ b2,
                        float* __restrict__ out, int n) {
    __shared__ float wl[64 * 64];
    __shared__ float hl[256];
    int tid = threadIdx.x;
#pragma unroll
    for (int i = 0; i < 16; ++i) wl[tid + 256 * i] = W1[tid + 256 * i];
    int v = blockIdx.x * 4 + (tid >> 6);
    int j = tid & 63;
    bool valid = v < n;
    hl[tid] = valid ? h[(size_t)v * 64 + j] : 0.f;
    __syncthreads();
    float acc = b1[j];
    const float* hr = &hl[(tid >> 6) << 6];
#pragma unroll
    for (int k = 0; k < 64; ++k) acc += hr[k] * wl[k * 64 + j];
    float tj = fmaxf(acc, 0.f);
    float p0 = tj * W2[j * 4 + 0];
    float p1 = tj * W2[j * 4 + 1];
    float p2 = tj * W2[j * 4 + 2];
    float p3 = tj * W2[j * 4 + 3];
#pragma unroll
    for (int m = 32; m >= 1; m >>= 1) {
        p0 += __shfl_xor(p0, m, 64);
        p1 += __shfl_xor(p1, m, 64);
        p2 += __shfl_xor(p2, m, 64);
        p3 += __shfl_xor(p3, m, 64);
    }
    if (valid && j < 4) {
        float p = (j == 0) ? p0 : (j == 1) ? p1 : (j == 2) ? p2 : p3;
        out[v * 4 + j] = x[v * 4 + j] + p + b2[j];
    }
}

extern "C" void kernel_launch(void* const* d_in, const int* in_sizes, int n_in,
                              void* d_out, int out_size, void* d_ws, size_t ws_size,
                              hipStream_t stream) {
    const float* x     = (const float*)d_in[0];
    const int*   eidx  = (const int*)  d_in[1];
    const float* Win   = (const float*)d_in[2];
    const float* bin   = (const float*)d_in[3];
    const float* convw = (const float*)d_in[4];
    const float* convb = (const float*)d_in[5];
    const float* gamma = (const float*)d_in[6];
    const float* beta  = (const float*)d_in[7];
    const float* mean  = (const float*)d_in[8];
    const float* var   = (const float*)d_in[9];
    const float* W1    = (const float*)d_in[10];
    const float* b1    = (const float*)d_in[11];
    const float* W2    = (const float*)d_in[12];
    const float* b2    = (const float*)d_in[13];
    float* out = (float*)d_out;

    int n = in_sizes[0] / 4;   // 50000
    int E = in_sizes[1] / 2;   // 800000
    const int B = 256;
    int NB = (n + B - 1) / B;  // 196 blocks for the scan

    // workspace layout:
    // dinv[n] f32 | h[n*64] f32 | hws[n*64] bf16 | counts[n] | cursor[n] |
    // tmp[n] | rowptr[n+1] | bsum[256] | boff[256] | col[E]
    char* p = (char*)d_ws;
    size_t nh = (size_t)n * 64;
    float*          dinv   = (float*)p;          p += ((size_t)n + 16) * 4;
    float*          h      = (float*)p;          p += nh * 4;
    unsigned short* hws    = (unsigned short*)p; p += nh * 2;
    int*            counts = (int*)p;            p += (size_t)n * 4;
    int*            cursor = (int*)p;            p += (size_t)n * 4;
    int*            tmp    = (int*)p;            p += (size_t)n * 4;
    int*            rowptr = (int*)p;            p += ((size_t)n + 16) * 4;
    int*            bsum   = (int*)p;            p += 256 * 4;
    int*            boff   = (int*)p;            p += 256 * 4;
    int*            col    = (int*)p;            p += (size_t)E * 4;

    // ---- CSR build ----
    zero2<<<NB, B, 0, stream>>>(counts, cursor, n);
    hist_dst<<<(E + B - 1) / B, B, 0, stream>>>(eidx + E, counts, E);
    scan1<<<NB, B, 0, stream>>>(counts, tmp, bsum, dinv, n);
    scan2<<<1, B, 0, stream>>>(bsum, boff, NB);
    scan3b<<<NB, B, 0, stream>>>(counts, tmp, boff, rowptr, n, E);
    csr_fill<<<(E + B - 1) / B, B, 0, stream>>>(eidx, rowptr, cursor, col, E);

    // ---- network ----
    input_proj<<<(int)((nh + B - 1) / B), B, 0, stream>>>(x, Win, bin, h, n);
    for (int i = 0; i < 3; ++i) {
        gemm_hws<<<(n + 31) / 32, B, 0, stream>>>(h, convw + i * 4096, dinv, hws, n);
        gather_finalize<<<(int)((nh + B - 1) / B), B, 0, stream>>>(
            rowptr, col, hws, dinv, h,
            convb + i * 64, gamma + i * 64, beta + i * 64, mean + i * 64, var + i * 64, n);
    }
    mlp_out<<<(n + 3) / 4, B, 0, stream>>>(h, x, W1, b1, W2, b2, out, n);
}

// Round 4
// 392.925 us; speedup vs baseline: 3.1405x; 3.1405x over previous
//
#include <hip/hip_runtime.h>

#define HID 64

__device__ __forceinline__ float bf2f(unsigned short u) {
    return __uint_as_float(((unsigned)u) << 16);
}
__device__ __forceinline__ unsigned short f2bf(float f) {
    unsigned u = __float_as_uint(f);
    u += 0x7FFF + ((u >> 16) & 1);  // RNE
    return (unsigned short)(u >> 16);
}

// ================= CSR build =================
__global__ void zero2(int* counts, int* cursor, int n) {
    int i = blockIdx.x * blockDim.x + threadIdx.x;
    if (i < n) { counts[i] = 0; cursor[i] = 0; }
}

__global__ void hist_dst(const int* __restrict__ dst, int* counts, int E) {
    int e = blockIdx.x * blockDim.x + threadIdx.x;
    if (e < E) atomicAdd(&counts[dst[e]], 1);
}

// per-block inclusive scan of counts -> tmp; block totals -> bsum; also dinv
__global__ void scan1(const int* __restrict__ counts, int* __restrict__ tmp,
                      int* __restrict__ bsum, float* __restrict__ dinv, int n) {
    __shared__ int s[256];
    int t = threadIdx.x;
    int i = blockIdx.x * 256 + t;
    int v = (i < n) ? counts[i] : 0;
    if (i < n) dinv[i] = rsqrtf((float)v + 1.0f);  // deg incl. self-loop
    s[t] = v;
    __syncthreads();
#pragma unroll
    for (int d = 1; d < 256; d <<= 1) {
        int x = (t >= d) ? s[t - d] : 0;
        __syncthreads();
        s[t] += x;
        __syncthreads();
    }
    if (i < n) tmp[i] = s[t];
    if (t == 255) bsum[blockIdx.x] = s[255];
}

// exclusive scan of block sums (NB <= 256)
__global__ void scan2(const int* __restrict__ bsum, int* __restrict__ boff, int nb) {
    __shared__ int s[256];
    int t = threadIdx.x;
    s[t] = (t < nb) ? bsum[t] : 0;
    __syncthreads();
#pragma unroll
    for (int d = 1; d < 256; d <<= 1) {
        int x = (t >= d) ? s[t - d] : 0;
        __syncthreads();
        s[t] += x;
        __syncthreads();
    }
    if (t < nb) boff[t] = s[t] - bsum[t];  // exclusive
}

__global__ void scan3b(const int* __restrict__ counts, const int* __restrict__ tmp,
                       const int* __restrict__ boff, int* __restrict__ rowptr, int n, int E) {
    int b = blockIdx.x;
    int i = b * 256 + threadIdx.x;
    if (i < n) rowptr[i] = tmp[i] - counts[i] + boff[b];
    if (i == n - 1) rowptr[n] = tmp[i] + boff[b];  // == E
}

// bucket-fill CSR: col = src only (coef folded into hws)
__global__ void csr_fill(const int* __restrict__ eidx, const int* __restrict__ rowptr,
                         int* __restrict__ cursor, int* __restrict__ col, int E) {
    int e = blockIdx.x * blockDim.x + threadIdx.x;
    if (e >= E) return;
    int s = eidx[e];
    int d = eidx[E + e];
    int pos = rowptr[d] + atomicAdd(&cursor[d], 1);
    col[pos] = s;
}

// ================= dense ops =================
__global__ void input_proj(const float* __restrict__ x, const float* __restrict__ Win,
                           const float* __restrict__ bin, float* __restrict__ h, int n) {
    int t = blockIdx.x * blockDim.x + threadIdx.x;
    int v = t >> 6, j = t & 63;
    if (v >= n) return;
    float acc = bin[j];
#pragma unroll
    for (int k = 0; k < 4; ++k) acc += x[v * 4 + k] * Win[k * 64 + j];
    h[t] = acc;
}

// hws = (h @ W) * dinv stored bf16.  Proven R2 structure: 4 rows/block,
// W staged in LDS, single accumulator, wave-uniform broadcast h reads.
// (R3's 8-acc float2 unroll spilled to scratch: 1 GB HBM traffic, 20x slower.)
__global__ void gemm_hws(const float* __restrict__ h, const float* __restrict__ W,
                         const float* __restrict__ dinv, unsigned short* __restrict__ hws,
                         int n) {
    __shared__ float wl[64 * 64];
    __shared__ float hl[256];
    int tid = threadIdx.x;
#pragma unroll
    for (int i = 0; i < 16; ++i) wl[tid + 256 * i] = W[tid + 256 * i];
    int v = blockIdx.x * 4 + (tid >> 6);
    int j = tid & 63;
    bool valid = v < n;
    hl[tid] = valid ? h[(size_t)v * 64 + j] : 0.f;
    __syncthreads();
    if (!valid) return;
    const float* hr = &hl[(tid >> 6) << 6];  // wave-uniform -> LDS broadcast
    float acc = 0.f;
#pragma unroll
    for (int k = 0; k < 64; ++k) acc += hr[k] * wl[k * 64 + j];  // 2-way alias: free
    hws[(size_t)v * 64 + j] = f2bf(acc * dinv[v]);
}

// pull aggregate (bf16 messages) + bias + BN(eval) + ReLU + residual; one wave per node
__global__ void gather_finalize(const int* __restrict__ rowptr, const int* __restrict__ col,
                                const unsigned short* __restrict__ hws,
                                const float* __restrict__ dinv, float* __restrict__ h,
                                const float* __restrict__ cb, const float* __restrict__ gamma,
                                const float* __restrict__ beta, const float* __restrict__ mean,
                                const float* __restrict__ var, int n) {
    int t = blockIdx.x * blockDim.x + threadIdx.x;
    int v = t >> 6;
    if (v >= n) return;
    int j = t & 63;
    int beg = rowptr[v], end = rowptr[v + 1];
    float sum = bf2f(hws[(size_t)v * 64 + j]);  // self-loop (already * dinv[v])
    int e = beg;
    for (; e + 3 < end; e += 4) {  // 4-way ILP
        int s0 = col[e], s1 = col[e + 1], s2 = col[e + 2], s3 = col[e + 3];
        float v0 = bf2f(hws[(size_t)s0 * 64 + j]);
        float v1 = bf2f(hws[(size_t)s1 * 64 + j]);
        float v2 = bf2f(hws[(size_t)s2 * 64 + j]);
        float v3 = bf2f(hws[(size_t)s3 * 64 + j]);
        sum += v0 + v1 + v2 + v3;
    }
    for (; e < end; ++e) sum += bf2f(hws[(size_t)col[e] * 64 + j]);
    float a = sum * dinv[v] + cb[j];
    a = (a - mean[j]) * rsqrtf(var[j] + 1e-5f) * gamma[j] + beta[j];
    a = fmaxf(a, 0.f);
    h[t] = a + h[t];  // residual: h still holds pre-conv value
}

// out = x + relu(h@W1+b1) @ W2 + b2 ; one wave per node
__global__ void mlp_out(const float* __restrict__ h, const float* __restrict__ x,
                        const float* __restrict__ W1, const float* __restrict__ b1,
                        const float* __restrict__ W2, const float* __restrict__ b2,
                        float* __restrict__ out, int n) {
    __shared__ float wl[64 * 64];
    __shared__ float hl[256];
    int tid = threadIdx.x;
#pragma unroll
    for (int i = 0; i < 16; ++i) wl[tid + 256 * i] = W1[tid + 256 * i];
    int v = blockIdx.x * 4 + (tid >> 6);
    int j = tid & 63;
    bool valid = v < n;
    hl[tid] = valid ? h[(size_t)v * 64 + j] : 0.f;
    __syncthreads();
    float acc = b1[j];
    const float* hr = &hl[(tid >> 6) << 6];
#pragma unroll
    for (int k = 0; k < 64; ++k) acc += hr[k] * wl[k * 64 + j];
    float tj = fmaxf(acc, 0.f);
    float p0 = tj * W2[j * 4 + 0];
    float p1 = tj * W2[j * 4 + 1];
    float p2 = tj * W2[j * 4 + 2];
    float p3 = tj * W2[j * 4 + 3];
#pragma unroll
    for (int m = 32; m >= 1; m >>= 1) {
        p0 += __shfl_xor(p0, m, 64);
        p1 += __shfl_xor(p1, m, 64);
        p2 += __shfl_xor(p2, m, 64);
        p3 += __shfl_xor(p3, m, 64);
    }
    if (valid && j < 4) {
        float p = (j == 0) ? p0 : (j == 1) ? p1 : (j == 2) ? p2 : p3;
        out[v * 4 + j] = x[v * 4 + j] + p + b2[j];
    }
}

extern "C" void kernel_launch(void* const* d_in, const int* in_sizes, int n_in,
                              void* d_out, int out_size, void* d_ws, size_t ws_size,
                              hipStream_t stream) {
    const float* x     = (const float*)d_in[0];
    const int*   eidx  = (const int*)  d_in[1];
    const float* Win   = (const float*)d_in[2];
    const float* bin   = (const float*)d_in[3];
    const float* convw = (const float*)d_in[4];
    const float* convb = (const float*)d_in[5];
    const float* gamma = (const float*)d_in[6];
    const float* beta  = (const float*)d_in[7];
    const float* mean  = (const float*)d_in[8];
    const float* var   = (const float*)d_in[9];
    const float* W1    = (const float*)d_in[10];
    const float* b1    = (const float*)d_in[11];
    const float* W2    = (const float*)d_in[12];
    const float* b2    = (const float*)d_in[13];
    float* out = (float*)d_out;

    int n = in_sizes[0] / 4;   // 50000
    int E = in_sizes[1] / 2;   // 800000
    const int B = 256;
    int NB = (n + B - 1) / B;  // 196 blocks for the scan

    // workspace layout:
    // dinv[n] f32 | h[n*64] f32 | hws[n*64] bf16 | counts[n] | cursor[n] |
    // tmp[n] | rowptr[n+1] | bsum[256] | boff[256] | col[E]
    char* p = (char*)d_ws;
    size_t nh = (size_t)n * 64;
    float*          dinv   = (float*)p;          p += ((size_t)n + 16) * 4;
    float*          h      = (float*)p;          p += nh * 4;
    unsigned short* hws    = (unsigned short*)p; p += nh * 2;
    int*            counts = (int*)p;            p += (size_t)n * 4;
    int*            cursor = (int*)p;            p += (size_t)n * 4;
    int*            tmp    = (int*)p;            p += (size_t)n * 4;
    int*            rowptr = (int*)p;            p += ((size_t)n + 16) * 4;
    int*            bsum   = (int*)p;            p += 256 * 4;
    int*            boff   = (int*)p;            p += 256 * 4;
    int*            col    = (int*)p;            p += (size_t)E * 4;

    // ---- CSR build ----
    zero2<<<NB, B, 0, stream>>>(counts, cursor, n);
    hist_dst<<<(E + B - 1) / B, B, 0, stream>>>(eidx + E, counts, E);
    scan1<<<NB, B, 0, stream>>>(counts, tmp, bsum, dinv, n);
    scan2<<<1, B, 0, stream>>>(bsum, boff, NB);
    scan3b<<<NB, B, 0, stream>>>(counts, tmp, boff, rowptr, n, E);
    csr_fill<<<(E + B - 1) / B, B, 0, stream>>>(eidx, rowptr, cursor, col, E);

    // ---- network ----
    input_proj<<<(int)((nh + B - 1) / B), B, 0, stream>>>(x, Win, bin, h, n);
    for (int i = 0; i < 3; ++i) {
        gemm_hws<<<(n + 3) / 4, B, 0, stream>>>(h, convw + i * 4096, dinv, hws, n);
        gather_finalize<<<(int)((nh + B - 1) / B), B, 0, stream>>>(
            rowptr, col, hws, dinv, h,
            convb + i * 64, gamma + i * 64, beta + i * 64, mean + i * 64, var + i * 64, n);
    }
    mlp_out<<<(n + 3) / 4, B, 0, stream>>>(h, x, W1, b1, W2, b2, out, n);
}